// Round 1
// baseline (75.659 us; speedup 1.0000x reference)
//
#include <hip/hip_runtime.h>
#include <math.h>

// FBPINN PoU: S=64 subdomains, N=65536 points, W=64.
// Round 14: TWO kernels (was 3). r12/r13 proved software grid barriers cost
// ~50 us on this part regardless of topology -> fusion dead. r13's residual
// pinned the harness floor at ~64 us; r11's 3 kernels + gaps = ~14 us
// controllable. This round removes one graph node: drop the F-table and do
// the r9-verified direct 12-subnet combine as kernel 2.
//   eval_grid: r11 verbatim. MFMA f16 layers 1/2; GK=1280, WIDTH=256;
//              block = (subdomain, 64-pt chunk) = 256 blocks.
//   combine:   per-point 12-subnet Gaussian PoU + lerp from U + hard BC.
// (Round 15: resubmitted unchanged — round-14 bench was an infra failure,
//  no counters; re-establish baseline before editing.)

#define GK     1280
#define WIDTH  256
#define HALFW  128
#define SW     36      // u32 words per LDS row: 32 data + 4 pad = 144 B

typedef _Float16 half8  __attribute__((ext_vector_type(8)));
typedef __fp16   fp16x2 __attribute__((ext_vector_type(2)));
typedef float    f32x4  __attribute__((ext_vector_type(4)));

__device__ __forceinline__ int glo_of(int s) {
    int g = (s * GK + 31) / 63 - HALFW;
    g = g < 0 ? 0 : g;
    const int hi = GK - (WIDTH - 1);
    g = g > hi ? hi : g;
    return g;
}

__device__ __forceinline__ float tanh_fast(float v) {
    // tanh(v) = 1 - 2/(exp(2v)+1); |v| <= ~7 here.
    float e = __expf(2.0f * v);
    return 1.0f - 2.0f * __builtin_amdgcn_rcpf(e + 1.0f);
}

__device__ __forceinline__ unsigned pkh(float a, float b) {
    fp16x2 h = __builtin_amdgcn_cvt_pkrtz(a, b);   // a->lo, b->hi
    return __builtin_bit_cast(unsigned, h);
}

// ---------------------------------------------------------------------------
// Kernel 1: eval subnet tables. 64 subdomains x 4 chunks = 256 blocks.
// ---------------------------------------------------------------------------
__global__ __launch_bounds__(256, 4) void eval_grid(
    const float* __restrict__ W0, const float* __restrict__ b0,
    const float* __restrict__ W1, const float* __restrict__ b1,
    const float* __restrict__ W2, const float* __restrict__ b2,
    const float* __restrict__ W3, const float* __restrict__ b3,
    float* __restrict__ U)
{
    const int tid  = (int)threadIdx.x;
    const int lane = tid & 63;
    const int wv   = __builtin_amdgcn_readfirstlane(tid >> 6);
    const int quad = lane >> 4;
    const int a16  = lane & 15;

    const int s     = blockIdx.x & 63;
    const int chunk = blockIdx.x >> 6;           // 0..3
    const int glo   = glo_of(s);
    const float x   = (float)(glo + chunk * 64 + lane) * (1.0f / (float)GK);

    __shared__ unsigned HtA[64 * SW];   // h0, f16-pairs, rows = p
    __shared__ unsigned HtB[64 * SW];   // h1
    __shared__ unsigned Wa1[64 * SW];   // W1 f16, rows = v (A layout)
    __shared__ unsigned Wa2[64 * SW];
    __shared__ float    Pw[4][4][16];   // layer-3 partials [wv][ni][a16]

    // ---- stage W1, W2 as f16 rows (coalesced float4 loads)
    const float4* __restrict__ g1 = (const float4*)(W1 + s * 4096);
    const float4* __restrict__ g2 = (const float4*)(W2 + s * 4096);
#pragma unroll
    for (int q = 0; q < 4; ++q) {
        int li = q * 256 + tid;              // float4 index 0..1023
        int v  = li >> 4;                    // row
        int wd = 2 * (li & 15);              // word col
        float4 f1 = g1[li];
        float4 f2 = g2[li];
        Wa1[v * SW + wd]     = pkh(f1.x, f1.y);
        Wa1[v * SW + wd + 1] = pkh(f1.z, f1.w);
        Wa2[v * SW + wd]     = pkh(f2.x, f2.y);
        Wa2[v * SW + wd + 1] = pkh(f2.z, f2.w);
    }

    // ---- layer 0
    const float* __restrict__ w0  = W0 + s * 64;
    const float* __restrict__ bb0 = b0 + s * 64;
#pragma unroll
    for (int j = 0; j < 16; j += 2) {
        int v = 16 * wv + j;
        float h0 = tanh_fast(fmaf(w0[v],     x, bb0[v]));
        float h1 = tanh_fast(fmaf(w0[v + 1], x, bb0[v + 1]));
        HtA[lane * SW + (v >> 1)] = pkh(h0, h1);
    }
    __syncthreads();                         // h0 + Wa1 + Wa2 visible

    const int vbase = 16 * wv + 4 * quad;
    f32x4 acc[4];

    // ================= layer 1 (MFMA) =================
    {
        const float* __restrict__ b1g = b1 + s * 64;
        float bv[4];
#pragma unroll
        for (int r = 0; r < 4; ++r) bv[r] = b1g[vbase + r];
#pragma unroll
        for (int ni = 0; ni < 4; ++ni)
#pragma unroll
            for (int r = 0; r < 4; ++r) acc[ni][r] = bv[r];

        half8 afr[2];
#pragma unroll
        for (int ks = 0; ks < 2; ++ks)
            afr[ks] = *(const half8*)&Wa1[(16 * wv + a16) * SW + 16 * ks + 4 * quad];
#pragma unroll
        for (int ni = 0; ni < 4; ++ni) {
#pragma unroll
            for (int ks = 0; ks < 2; ++ks) {
                half8 bfr = *(const half8*)&HtA[(16 * ni + a16) * SW + 16 * ks + 4 * quad];
                acc[ni] = __builtin_amdgcn_mfma_f32_16x16x32_f16(afr[ks], bfr, acc[ni], 0, 0, 0);
            }
        }
#pragma unroll
        for (int ni = 0; ni < 4; ++ni) {
            int row  = (16 * ni + a16) * SW;
            int colb = 8 * wv + 2 * quad;
            HtB[row + colb]     = pkh(tanh_fast(acc[ni][0]), tanh_fast(acc[ni][1]));
            HtB[row + colb + 1] = pkh(tanh_fast(acc[ni][2]), tanh_fast(acc[ni][3]));
        }
    }
    __syncthreads();                         // h1 visible

    // ================= layer 2 (MFMA) =================
    {
        const float* __restrict__ b2g = b2 + s * 64;
        float bv[4];
#pragma unroll
        for (int r = 0; r < 4; ++r) bv[r] = b2g[vbase + r];
#pragma unroll
        for (int ni = 0; ni < 4; ++ni)
#pragma unroll
            for (int r = 0; r < 4; ++r) acc[ni][r] = bv[r];

        half8 afr[2];
#pragma unroll
        for (int ks = 0; ks < 2; ++ks)
            afr[ks] = *(const half8*)&Wa2[(16 * wv + a16) * SW + 16 * ks + 4 * quad];
#pragma unroll
        for (int ni = 0; ni < 4; ++ni) {
#pragma unroll
            for (int ks = 0; ks < 2; ++ks) {
                half8 bfr = *(const half8*)&HtB[(16 * ni + a16) * SW + 16 * ks + 4 * quad];
                acc[ni] = __builtin_amdgcn_mfma_f32_16x16x32_f16(afr[ks], bfr, acc[ni], 0, 0, 0);
            }
        }
    }

    // ================= layer 3 =================
    {
        const float* __restrict__ w3g = W3 + s * 64;
        float w3r[4];
#pragma unroll
        for (int r = 0; r < 4; ++r) w3r[r] = w3g[vbase + r];
#pragma unroll
        for (int ni = 0; ni < 4; ++ni) {
            float pu = 0.0f;
#pragma unroll
            for (int r = 0; r < 4; ++r)
                pu = fmaf(w3r[r], tanh_fast(acc[ni][r]), pu);
            pu += __shfl_xor(pu, 16);
            pu += __shfl_xor(pu, 32);
            if (quad == 0) Pw[wv][ni][a16] = pu;
        }
    }
    __syncthreads();

    if (tid < 64) {
        float u = b3[s];
#pragma unroll
        for (int w = 0; w < 4; ++w) u += Pw[w][tid >> 4][tid & 15];
        U[s * WIDTH + chunk * 64 + tid] = u;
    }
}

// ---------------------------------------------------------------------------
// Kernel 2: per-point 12-subnet Gaussian PoU combine + hard BC (r9 math).
// ---------------------------------------------------------------------------
__global__ __launch_bounds__(256) void combine(
    const float* __restrict__ x_in, const float* __restrict__ U,
    float* __restrict__ out, int N)
{
    int n = blockIdx.x * 256 + (int)threadIdx.x;
    if (n >= N) return;
    float x = x_in[n];

    int jf = (int)floorf(x * 63.0f);
    int lo = jf - 5;
    lo = lo < 0 ? 0 : (lo > 52 ? 52 : lo);

    const float inv_sigma = 64.0f / 1.5f;
    const float t_all = x * (float)GK;

    float u0v[12], u1v[12], fracv[12], wvv[12];
#pragma unroll
    for (int k = 0; k < 12; ++k) {
        int s = lo + k;
        int glo = glo_of(s);
        float t = t_all - (float)glo;
        int it = (int)floorf(t);
        it = it < 0 ? 0 : (it > WIDTH - 2 ? WIDTH - 2 : it);
        fracv[k] = t - (float)it;
        const float* __restrict__ row = U + s * WIDTH + it;
        u0v[k] = row[0];
        u1v[k] = row[1];
        float d = (x - (float)s * (1.0f / 63.0f)) * inv_sigma;
        wvv[k] = __expf(-0.5f * d * d);
    }

    float num = 0.0f, den = 0.0f;
#pragma unroll
    for (int k = 0; k < 12; ++k) {
        float u = fmaf(fracv[k], u1v[k] - u0v[k], u0v[k]);
        num = fmaf(wvv[k], u, num);
        den += wvv[k];
    }

    out[n] = tanh_fast(5.0f * x) * num * __builtin_amdgcn_rcpf(den);
}

// ---------------------------------------------------------------------------
extern "C" void kernel_launch(void* const* d_in, const int* in_sizes, int n_in,
                              void* d_out, int out_size, void* d_ws, size_t ws_size,
                              hipStream_t stream) {
    const float* x  = (const float*)d_in[0];
    const float* W0 = (const float*)d_in[1];
    const float* b0 = (const float*)d_in[2];
    const float* W1 = (const float*)d_in[3];
    const float* b1 = (const float*)d_in[4];
    const float* W2 = (const float*)d_in[5];
    const float* b2 = (const float*)d_in[6];
    const float* W3 = (const float*)d_in[7];
    const float* b3 = (const float*)d_in[8];

    float* U   = (float*)d_ws;              // 64*256*4 B = 64 KiB
    float* out = (float*)d_out;

    eval_grid<<<dim3(256), dim3(256), 0, stream>>>(
        W0, b0, W1, b1, W2, b2, W3, b3, U);
    combine<<<dim3(256), dim3(256), 0, stream>>>(x, U, out, 65536);
}